// Round 5
// baseline (183.436 us; speedup 1.0000x reference)
//
#include <hip/hip_runtime.h>
#include <math.h>
#include <stdint.h>

#define K_DIM 8192     // S*DIM
#define D_DIM 2048
#define M_ROWS 8192
#define N_W 32         // W columns (only 24 used in H)
#define NC 24
#define KSPLIT 8
#define KRANGE (K_DIM / KSPLIT)     // 1024 k per block
#define NKSTEP (KRANGE / 32)        // 32 k-steps per block
#define TOTAL_KSTEPS (K_DIM / 32)   // 256

typedef short bf16x8 __attribute__((ext_vector_type(8)));
typedef float f32x4 __attribute__((ext_vector_type(4)));
union U32x4 { uint32_t u[4]; bf16x8 v; };

// wfrag layout (u16): [ks][tile(2)][hilo(2)][lane(64)][e(8)]  -> 1 MB total.
// Fragment for (ks,tile,hilo) is a contiguous 1KB block; lane l reads 16B at
// l*16 -> wave reads the whole 1KB coalesced; L2-resident across all blocks.
#define WFRAG_IDX(ks, tile, hilo) ((((ks) * 2 + (tile)) * 2 + (hilo)) * 64)

// ---------------------------------------------------------------------------
// Kernel 0: prepack W -> bf16 hi/lo B-fragments (once), and zero Hsum.
// Thread per (k,n). k-map matches the A-fragment map used in the gemm:
// lane = ((k&31)>>3)*16 + (n&15), e = k&7  (same permutation both sides).
// ---------------------------------------------------------------------------
__global__ __launch_bounds__(256) void mhc_prepack_kernel(
    const float* __restrict__ W, unsigned short* __restrict__ wfrag,
    float* __restrict__ Hsum)
{
    const int idx = blockIdx.x * 256 + threadIdx.x;   // 0 .. 262143
    const int k = idx >> 5, n = idx & 31;
    const float w = W[(size_t)k * N_W + n];
    const uint32_t u = __float_as_uint(w);
    const float hif = __uint_as_float(u & 0xFFFF0000u);
    const uint32_t ur = __float_as_uint(w - hif);

    const int ks = k >> 5, kk = k & 31;
    const int lane = ((kk >> 3) << 4) | (n & 15);
    const int e = kk & 7;
    const int tile = n >> 4;
    unsigned short* p = wfrag + ((size_t)WFRAG_IDX(ks, tile, 0) + lane) * 8 + e;
    p[0]   = (unsigned short)(u >> 16);    // hi  (hilo stride = 64*8 = 512)
    p[512] = (unsigned short)(ur >> 16);   // lo

    if (idx < M_ROWS * NC) Hsum[idx] = 0.f;
}

// ---------------------------------------------------------------------------
// Kernel 1: H[m,0:24] partial GEMM via MFMA, bf16 hi/lo split.
//   H = Xhi@Whi + Xlo@Whi + Xhi@Wlo   (Xlo@Wlo dropped)
// No LDS, no barriers: per k-step a lane loads 8 fp32 of its own row
// (2x dwordx4, the real HBM stream), 4x 16B W-fragments (L2 broadcast),
// converts X to hi/lo bf16 in-register, issues 6 MFMA.
// Block = 256 thr (4 waves); wave owns 16 rows; grid = (128 rowblk, 8 ksplit).
// C/D layout: D[row=(l>>4)*4+reg][col=l&15] [HW-verified]; fp32 atomic combine.
// ---------------------------------------------------------------------------
__global__ __launch_bounds__(256) void mhc_gemm_kernel(
    const float* __restrict__ X, const unsigned short* __restrict__ wfrag,
    float* __restrict__ Hsum)
{
    const int t = threadIdx.x;
    const int l = t & 63;
    const int wv = t >> 6;
    const int rowbase = blockIdx.x * 64;
    const int ks0 = blockIdx.y * NKSTEP;

    f32x4 c0 = {0.f, 0.f, 0.f, 0.f};
    f32x4 c1 = {0.f, 0.f, 0.f, 0.f};

    const int arow = rowbase + wv * 16 + (l & 15);
    const float* __restrict__ xrow = X + (size_t)arow * K_DIM + ((l >> 4) * 8);
    const bf16x8* __restrict__ wf = reinterpret_cast<const bf16x8*>(wfrag);

#pragma unroll 2
    for (int s = 0; s < NKSTEP; ++s) {
        const int ks = ks0 + s;
        const float* xc = xrow + ks * 32;
        const float4 xa = *reinterpret_cast<const float4*>(xc);
        const float4 xb = *reinterpret_cast<const float4*>(xc + 4);
        float xs[8];
        xs[0] = xa.x; xs[1] = xa.y; xs[2] = xa.z; xs[3] = xa.w;
        xs[4] = xb.x; xs[5] = xb.y; xs[6] = xb.z; xs[7] = xb.w;

        U32x4 ah, al;
#pragma unroll
        for (int p = 0; p < 4; ++p) {
            const uint32_t u0 = __float_as_uint(xs[2 * p]);
            const uint32_t u1 = __float_as_uint(xs[2 * p + 1]);
            const float h0 = __uint_as_float(u0 & 0xFFFF0000u);
            const float h1 = __uint_as_float(u1 & 0xFFFF0000u);
            const uint32_t r0 = __float_as_uint(xs[2 * p] - h0);
            const uint32_t r1 = __float_as_uint(xs[2 * p + 1] - h1);
            ah.u[p] = (u1 & 0xFFFF0000u) | (u0 >> 16);
            al.u[p] = (r1 & 0xFFFF0000u) | (r0 >> 16);
        }

        const bf16x8 bh0 = wf[WFRAG_IDX(ks, 0, 0) + l];
        const bf16x8 bl0 = wf[WFRAG_IDX(ks, 0, 1) + l];
        const bf16x8 bh1 = wf[WFRAG_IDX(ks, 1, 0) + l];
        const bf16x8 bl1 = wf[WFRAG_IDX(ks, 1, 1) + l];

        c0 = __builtin_amdgcn_mfma_f32_16x16x32_bf16(ah.v, bh0, c0, 0, 0, 0);
        c0 = __builtin_amdgcn_mfma_f32_16x16x32_bf16(al.v, bh0, c0, 0, 0, 0);
        c0 = __builtin_amdgcn_mfma_f32_16x16x32_bf16(ah.v, bl0, c0, 0, 0, 0);
        c1 = __builtin_amdgcn_mfma_f32_16x16x32_bf16(ah.v, bh1, c1, 0, 0, 0);
        c1 = __builtin_amdgcn_mfma_f32_16x16x32_bf16(al.v, bh1, c1, 0, 0, 0);
        c1 = __builtin_amdgcn_mfma_f32_16x16x32_bf16(ah.v, bl1, c1, 0, 0, 0);
    }

    // ---- epilogue: D[row=(l>>4)*4+r][col=l&15]; atomic combine ----
    const int drow = rowbase + wv * 16 + (l >> 4) * 4;
    const int col = l & 15;
#pragma unroll
    for (int r = 0; r < 4; ++r)
        atomicAdd(&Hsum[(size_t)(drow + r) * NC + col], c0[r]);
    if (col < 8) {
#pragma unroll
        for (int r = 0; r < 4; ++r)
            atomicAdd(&Hsum[(size_t)(drow + r) * NC + 16 + col], c1[r]);
    }
}

// ---------------------------------------------------------------------------
// Kernel 2: params (transform + sinkhorn) + apply. One block per row.
// ---------------------------------------------------------------------------
__global__ __launch_bounds__(256) void mhc_apply_kernel(
    const float* __restrict__ X, const float* __restrict__ Hsum,
    const float* __restrict__ ab, float* __restrict__ out)
{
    __shared__ float pbuf[NC];
    const int row = blockIdx.x;
    const int t = threadIdx.x;

    if (t < 64) {
        const int lane = t;
        const float pl = (lane < NC) ? Hsum[(size_t)row * NC + lane] : 0.f;
        const float bias  = (lane < NC) ? ab[lane] : 0.f;
        const float scale = ab[(lane < 16) ? 24 : ((lane < 20) ? 25 : 26)];

        float vout;
        if (lane < 16) {
            vout = __expf(fmaf(scale, pl, bias));                 // exp(a_res*H+b)
        } else {
            vout = fmaf(scale, 1.f / (1.f + __expf(-pl)), bias);  // a*sigmoid(H)+b
        }

        // Sinkhorn on lanes 0..15: lane = s*4 + i.
        float p = vout;
        for (int it = 0; it < 20; ++it) {
            float rs = p + __shfl_xor(p, 1);
            rs += __shfl_xor(rs, 2);
            p = p / rs;
            float cs = p + __shfl_xor(p, 4);
            cs += __shfl_xor(cs, 8);
            p = p / cs;
        }
        if (lane < NC) pbuf[lane] = (lane < 16) ? p : vout;
    }
    __syncthreads();

    float hres[4][4], hpre[4], hpos[4];
#pragma unroll
    for (int i = 0; i < 16; ++i) hres[i >> 2][i & 3] = pbuf[i];
#pragma unroll
    for (int i = 0; i < 4; ++i) hpre[i] = pbuf[16 + i];
#pragma unroll
    for (int i = 0; i < 4; ++i) hpos[i] = pbuf[20 + i];

    const float4* __restrict__ Xr =
        reinterpret_cast<const float4*>(X + (size_t)row * K_DIM);
    float4* __restrict__ Or = reinterpret_cast<float4*>(out + (size_t)row * K_DIM);

#pragma unroll
    for (int q = 0; q < 2; ++q) {
        const int pos = t + q * 256;          // float4 index within a 2048-seg
        float4 xq[4];
#pragma unroll
        for (int i = 0; i < 4; ++i) xq[i] = Xr[i * (D_DIM / 4) + pos];

        float y[4];
#pragma unroll
        for (int e = 0; e < 4; ++e) {
            float s = 0.f;
#pragma unroll
            for (int i = 0; i < 4; ++i)
                s = fmaf(hpre[i], reinterpret_cast<const float*>(&xq[i])[e], s);
            y[e] = s;
        }

#pragma unroll
        for (int s = 0; s < 4; ++s) {
            float4 o;
            float* oe = reinterpret_cast<float*>(&o);
#pragma unroll
            for (int e = 0; e < 4; ++e) {
                float v = hpos[s] * y[e];
#pragma unroll
                for (int i = 0; i < 4; ++i)
                    v = fmaf(hres[s][i], reinterpret_cast<const float*>(&xq[i])[e], v);
                oe[e] = v;
            }
            Or[s * (D_DIM / 4) + pos] = o;
        }
    }
}

extern "C" void kernel_launch(void* const* d_in, const int* in_sizes, int n_in,
                              void* d_out, int out_size, void* d_ws, size_t ws_size,
                              hipStream_t stream) {
    const float* X  = (const float*)d_in[0];
    const float* W  = (const float*)d_in[1];
    const float* ab = (const float*)d_in[2];
    float* out = (float*)d_out;
    float* Hsum = (float*)d_ws;                               // 786,432 B
    unsigned short* wfrag = (unsigned short*)((char*)d_ws + (size_t)M_ROWS * NC * 4);
                                                              // + 1,048,576 B

    mhc_prepack_kernel<<<(K_DIM * N_W) / 256, 256, 0, stream>>>(W, wfrag, Hsum);
    dim3 g1(M_ROWS / 64, KSPLIT);
    mhc_gemm_kernel<<<g1, 256, 0, stream>>>(X, wfrag, Hsum);
    mhc_apply_kernel<<<M_ROWS, 256, 0, stream>>>(X, Hsum, ab, out);
}

// Round 6
// 182.389 us; speedup vs baseline: 1.0057x; 1.0057x over previous
//
#include <hip/hip_runtime.h>
#include <math.h>
#include <stdint.h>

#define K_DIM 8192     // S*DIM
#define D_DIM 2048
#define M_ROWS 8192
#define N_W 32         // W columns (only 24 used in H)
#define NC 24
#define RB 4           // rows per block
#define THREADS 512
#define TOTAL_KSTEPS (K_DIM / 32)   // 256

typedef short bf16x8 __attribute__((ext_vector_type(8)));
typedef float f32x4 __attribute__((ext_vector_type(4)));
union U32x4 { uint32_t u[4]; bf16x8 v; };

// wfrag layout (u16): [ks][tile(2)][hilo(2)][lane(64)][e(8)] -> 1 MB total.
// Fragment for (ks,tile,hilo) is a contiguous 1KB block; lane l reads 16B at
// l*16 -> wave reads 1KB coalesced; L2-resident for all blocks.
#define WFRAG_IDX(ks, tile, hilo) ((((ks) * 2 + (tile)) * 2 + (hilo)) * 64)

// ---------------------------------------------------------------------------
// Kernel 0: prepack W -> bf16 hi/lo B-fragments (once).
// k-map matches the A-fragment map: lane=((k&31)>>3)*16+(n&15), e=k&7.
// ---------------------------------------------------------------------------
__global__ __launch_bounds__(256) void mhc_prepack_kernel(
    const float* __restrict__ W, unsigned short* __restrict__ wfrag)
{
    const int idx = blockIdx.x * 256 + threadIdx.x;   // 0 .. 262143
    const int k = idx >> 5, n = idx & 31;
    const float w = W[(size_t)k * N_W + n];
    const uint32_t u = __float_as_uint(w);
    const float hif = __uint_as_float(u & 0xFFFF0000u);
    const uint32_t ur = __float_as_uint(w - hif);

    const int ks = k >> 5, kk = k & 31;
    const int lane = ((kk >> 3) << 4) | (n & 15);
    const int e = kk & 7;
    const int tile = n >> 4;
    unsigned short* p = wfrag + ((size_t)WFRAG_IDX(ks, tile, 0) + lane) * 8 + e;
    p[0]   = (unsigned short)(u >> 16);    // hi  (hilo stride = 64*8 = 512 u16)
    p[512] = (unsigned short)(ur >> 16);   // lo
}

// ---------------------------------------------------------------------------
// Fused kernel. Block = 512 thr (8 waves) owns RB=4 rows.
//  Phase 0: burst-load the 128KB X tile into regs: x4[row][seg] = row-seg
//           float4 at d4 = t  (this IS the apply-phase layout).
//  Phase 1: per seg-chunk: regs -> LDS [4][2048]; 8 waves MFMA full K
//           (wave wv: ks = i*64 + wv*8 + s), A rows = real row (l&3) wrap,
//           B = prepacked wfrag hi/lo (L2). H = Xhi*Whi + Xlo*Whi + Xhi*Wlo.
//  Phase 2: LDS-reduce 8 partial H's; wave 0: sigmoid cols + 20-iter
//           Sinkhorn for all 4 rows in parallel (16-lane groups); params->LDS.
//  Phase 3: apply from regs (thread-local einsum), write O.
// No atomics, no second X read: HBM = 256MB in + 256MB out.
// ---------------------------------------------------------------------------
__global__ __launch_bounds__(THREADS, 4) void mhc_fused_kernel(
    const float* __restrict__ X, const unsigned short* __restrict__ wfrag,
    const float* __restrict__ ab, float* __restrict__ out)
{
    __shared__ __align__(16) float Xl[RB * D_DIM];   // 32 KB chunk buffer
    __shared__ float Hpart[8][RB][NC];               // 3 KB
    __shared__ float pbuf[RB][NC];

    const int t = threadIdx.x;
    const int l = t & 63;
    const int wv = t >> 6;
    const int rowbase = blockIdx.x * RB;

    // ---- phase 0: burst-load X tile into registers (seg-major order) ----
    const float4* __restrict__ Xg = reinterpret_cast<const float4*>(X);
    float4 x4[RB][4];   // [row][seg] -- all indexing below is compile-time
#pragma unroll
    for (int i = 0; i < 4; ++i)
#pragma unroll
        for (int r = 0; r < RB; ++r)
            x4[r][i] = Xg[(size_t)(rowbase + r) * (K_DIM / 4) + i * 512 + t];

    // ---- phase 1: chunked LDS bounce + MFMA ----
    f32x4 c0 = {0.f, 0.f, 0.f, 0.f};
    f32x4 c1 = {0.f, 0.f, 0.f, 0.f};
    const bf16x8* __restrict__ wf = reinterpret_cast<const bf16x8*>(wfrag);
    const int abase = (l & 3) * D_DIM + ((l >> 4) << 3);  // A-frag float base

#pragma unroll
    for (int i = 0; i < 4; ++i) {
        if (i) __syncthreads();               // prior chunk's compute done
#pragma unroll
        for (int r = 0; r < RB; ++r)
            *reinterpret_cast<float4*>(&Xl[r * D_DIM + (t << 2)]) = x4[r][i];
        __syncthreads();

#pragma unroll
        for (int s = 0; s < 8; ++s) {
            const int ksl = wv * 8 + s;       // kstep within chunk (0..63)
            const int ks = i * 64 + ksl;      // global kstep
            const float* xp = &Xl[abase + ksl * 32];
            const float4 xa = *reinterpret_cast<const float4*>(xp);
            const float4 xb = *reinterpret_cast<const float4*>(xp + 4);
            float xs[8];
            xs[0] = xa.x; xs[1] = xa.y; xs[2] = xa.z; xs[3] = xa.w;
            xs[4] = xb.x; xs[5] = xb.y; xs[6] = xb.z; xs[7] = xb.w;

            U32x4 ah, al;
#pragma unroll
            for (int p = 0; p < 4; ++p) {
                const uint32_t u0 = __float_as_uint(xs[2 * p]);
                const uint32_t u1 = __float_as_uint(xs[2 * p + 1]);
                const float h0 = __uint_as_float(u0 & 0xFFFF0000u);
                const float h1 = __uint_as_float(u1 & 0xFFFF0000u);
                const uint32_t r0 = __float_as_uint(xs[2 * p] - h0);
                const uint32_t r1 = __float_as_uint(xs[2 * p + 1] - h1);
                ah.u[p] = (u1 & 0xFFFF0000u) | (u0 >> 16);
                al.u[p] = (r1 & 0xFFFF0000u) | (r0 >> 16);
            }

            const bf16x8 bh0 = wf[WFRAG_IDX(ks, 0, 0) + l];
            const bf16x8 bl0 = wf[WFRAG_IDX(ks, 0, 1) + l];
            const bf16x8 bh1 = wf[WFRAG_IDX(ks, 1, 0) + l];
            const bf16x8 bl1 = wf[WFRAG_IDX(ks, 1, 1) + l];

            c0 = __builtin_amdgcn_mfma_f32_16x16x32_bf16(ah.v, bh0, c0, 0, 0, 0);
            c0 = __builtin_amdgcn_mfma_f32_16x16x32_bf16(al.v, bh0, c0, 0, 0, 0);
            c0 = __builtin_amdgcn_mfma_f32_16x16x32_bf16(ah.v, bl0, c0, 0, 0, 0);
            c1 = __builtin_amdgcn_mfma_f32_16x16x32_bf16(ah.v, bh1, c1, 0, 0, 0);
            c1 = __builtin_amdgcn_mfma_f32_16x16x32_bf16(al.v, bh1, c1, 0, 0, 0);
            c1 = __builtin_amdgcn_mfma_f32_16x16x32_bf16(ah.v, bl1, c1, 0, 0, 0);
        }
    }

    // ---- phase 2: reduce partials, transform, sinkhorn ----
    __syncthreads();
    // D row = (l>>4)*4 + reg; real row = D row & 3. Lanes l<16 hold rows 0..3.
    if (l < 16) {
#pragma unroll
        for (int r = 0; r < RB; ++r) Hpart[wv][r][l] = c0[r];
    }
    if (l < 8) {
#pragma unroll
        for (int r = 0; r < RB; ++r) Hpart[wv][r][16 + l] = c1[r];
    }
    __syncthreads();

    if (wv == 0) {
        // residual cols: lane l -> (row = l>>4, col = l&15)
        float h0 = 0.f;
#pragma unroll
        for (int w = 0; w < 8; ++w) h0 += Hpart[w][l >> 4][l & 15];
        float p = __expf(fmaf(ab[24], h0, ab[l & 15]));   // exp(a_res*H+b_res)

        // sigmoid cols: lanes l<32 -> (row = l>>3, col = 16+(l&7))
        if (l < 32) {
            float h1 = 0.f;
#pragma unroll
            for (int w = 0; w < 8; ++w) h1 += Hpart[w][l >> 3][16 + (l & 7)];
            const int ci = 16 + (l & 7);
            const float sc = (ci < 20) ? ab[25] : ab[26];
            pbuf[l >> 3][ci] = fmaf(sc, 1.f / (1.f + __expf(-h1)), ab[ci]);
        }

        // Sinkhorn, 4 rows in parallel (16-lane groups; P idx = l&15 = s*4+i)
        for (int it = 0; it < 20; ++it) {
            float rs = p + __shfl_xor(p, 1);
            rs += __shfl_xor(rs, 2);
            p = p / rs;
            float cs = p + __shfl_xor(p, 4);
            cs += __shfl_xor(cs, 8);
            p = p / cs;
        }
        pbuf[l >> 4][l & 15] = p;
    }
    __syncthreads();

    // ---- phase 3: apply from registers, write O ----
    float4* __restrict__ Og = reinterpret_cast<float4*>(out);
#pragma unroll
    for (int r = 0; r < RB; ++r) {
        float hre[4][4], hpr[4], hpo[4];
#pragma unroll
        for (int q = 0; q < 16; ++q) hre[q >> 2][q & 3] = pbuf[r][q];
#pragma unroll
        for (int q = 0; q < 4; ++q) hpr[q] = pbuf[r][16 + q];
#pragma unroll
        for (int q = 0; q < 4; ++q) hpo[q] = pbuf[r][20 + q];

        float y[4];
#pragma unroll
        for (int e = 0; e < 4; ++e) {
            float v = 0.f;
#pragma unroll
            for (int i = 0; i < 4; ++i)
                v = fmaf(hpr[i], reinterpret_cast<const float*>(&x4[r][i])[e], v);
            y[e] = v;
        }

        const size_t ob = (size_t)(rowbase + r) * (K_DIM / 4);
#pragma unroll
        for (int s = 0; s < 4; ++s) {
            float4 o;
            float* oe = reinterpret_cast<float*>(&o);
#pragma unroll
            for (int e = 0; e < 4; ++e) {
                float v = hpo[s] * y[e];
#pragma unroll
                for (int i = 0; i < 4; ++i)
                    v = fmaf(hre[s][i],
                             reinterpret_cast<const float*>(&x4[r][i])[e], v);
                oe[e] = v;
            }
            Og[ob + s * 512 + t] = o;
        }
    }
}

extern "C" void kernel_launch(void* const* d_in, const int* in_sizes, int n_in,
                              void* d_out, int out_size, void* d_ws, size_t ws_size,
                              hipStream_t stream) {
    const float* X  = (const float*)d_in[0];
    const float* W  = (const float*)d_in[1];
    const float* ab = (const float*)d_in[2];
    float* out = (float*)d_out;
    unsigned short* wfrag = (unsigned short*)d_ws;   // 1,048,576 bytes

    mhc_prepack_kernel<<<(K_DIM * N_W) / 256, 256, 0, stream>>>(W, wfrag);
    mhc_fused_kernel<<<M_ROWS / RB, THREADS, 0, stream>>>(X, wfrag, ab, out);
}